// Round 24
// baseline (67.956 us; speedup 1.0000x reference)
//
#include <hip/hip_runtime.h>
#include <hip/hip_bf16.h>

typedef __attribute__((ext_vector_type(8))) short bf16x8;
typedef __attribute__((ext_vector_type(4))) float f32x4;
typedef __attribute__((ext_vector_type(2))) float f32x2;

#define B_ROWS 8192
#define NROWS 16384             // 2B
#define D 128
#define C1 2.8853900817779268f  // 2*log2(e)  (sim = 2*cos; exp(x)=2^(x*log2e))
#define E_M2 0.13533528323661270f // exp(-2) == 2^(-C1): the folded row-max shift
#define RSCALE 1.6986436f       // sqrt(C1), folded into reps on both operands
#define TILE_COLS 32
#define TILE_BYTES (TILE_COLS * D * 2) // 8 KB per buffer
#define NSPLIT 16               // lists per row-chunk
#define NBLK (64 * NSPLIT)      // 1024
#define NSLICE 8

// Raw hardware exp2/log2: args are bounded, no range handling needed.
__device__ __forceinline__ float fast_exp2(float x) {
#if __has_builtin(__builtin_amdgcn_exp2f)
    return __builtin_amdgcn_exp2f(x);
#else
    float r; asm("v_exp_f32 %0, %1" : "=v"(r) : "v"(x)); return r;
#endif
}
__device__ __forceinline__ float fast_log2(float x) {
#if __has_builtin(__builtin_amdgcn_logf)
    return __builtin_amdgcn_logf(x);
#else
    float r; asm("v_log_f32 %0, %1" : "=v"(r) : "v"(x)); return r;
#endif
}

__device__ __forceinline__ unsigned short f2bf(float f) {
    union { float f; unsigned u; } v; v.f = f;
    unsigned r = v.u + 0x7FFFu + ((v.u >> 16) & 1u); // RNE
    return (unsigned short)(r >> 16);
}

// triangular colpart offset: slab I holds cols [256(I+1), NROWS)
__device__ __host__ __forceinline__ int colpart_off(int I) {
    return I * NROWS - 128 * I * (I + 1);
}

// K1: row norms + positive dots + bf16 reps (pre-scaled by sqrt(C1)).
__global__ __launch_bounds__(256) void k_norm(const float* __restrict__ zi,
                                              const float* __restrict__ zj,
                                              unsigned* __restrict__ repsU,
                                              float* __restrict__ pos) {
    int w = threadIdx.x >> 6, lane = threadIdx.x & 63;
    int row = blockIdx.x * 4 + w;
    const float2* a2 = (const float2*)(zi + (size_t)row * D);
    const float2* b2 = (const float2*)(zj + (size_t)row * D);
    float2 a = a2[lane], b = b2[lane];
    float si = a.x * a.x + a.y * a.y;
    float sj = b.x * b.x + b.y * b.y;
    float sd = a.x * b.x + a.y * b.y;
#pragma unroll
    for (int m = 32; m; m >>= 1) {
        si += __shfl_xor(si, m);
        sj += __shfl_xor(sj, m);
        sd += __shfl_xor(sd, m);
    }
    float inv_i = 1.0f / fmaxf(sqrtf(si), 1e-12f);
    float inv_j = 1.0f / fmaxf(sqrtf(sj), 1e-12f);
    float sa = inv_i * RSCALE, sb = inv_j * RSCALE;
    repsU[(size_t)row * 64 + lane] =
        (unsigned)f2bf(a.x * sa) | ((unsigned)f2bf(a.y * sa) << 16);
    repsU[(size_t)(row + B_ROWS) * 64 + lane] =
        (unsigned)f2bf(b.x * sb) | ((unsigned)f2bf(b.y * sb) << 16);
    if (lane == 0) pos[row] = fast_exp2(sd * inv_i * inv_j * C1); // exp(2*cos_ij)
}

// K2: symmetric-half fused sim-GEMM + exp + row/col sums — R18 structure +
// T15 EPILOGUE DEFERRAL (the one untried mechanism): tile t's MFMA results
// stay in registers cv[2][4]; its exp/acc/csum runs at iter t+1 BETWEEN the
// ds_read issue and MFMA consumption of tile t+1, covering lgkm latency
// within the wave instead of extending the per-tile critical chain.
// Zero copies: cv is consumed by exp before the next MFMAs overwrite it.
// colacc pipeline shifts by one: csum(t-1) written at iter t (par (t-1)&1),
// flushed at iter t+1... i.e. flush at iter t handles tile t-2.
// C/D layout (m89-verified): row=(lane>>4)*4+q, col=lane&15.
__global__ __launch_bounds__(256, 2) void k_negsum(const unsigned short* __restrict__ R,
                                                   float* __restrict__ rowpart,
                                                   float* __restrict__ colpart) {
    __shared__ char smem[2][TILE_BYTES];    // 16 KB
    __shared__ float colacc[2][16][16][2];  // 4 KB [parity][w*4+lk][lr][ct]
    int I = blockIdx.x >> 4;
    int s = blockIdx.x & (NSPLIT - 1);
    int rowBase = I << 8;
    int j0 = I << 3;                        // first owned 32-col tile
    int dph = (s - (j0 & 15)) & 15;
    int jstart = j0 + dph;                  // first tile of this list
    int nt = (jstart < 512) ? (((511 - jstart) >> 4) + 1) : 0;

    int w = threadIdx.x >> 6;
    int lane = threadIdx.x & 63;
    int lr = lane & 15, lk = lane >> 4;
    int waveRow = rowBase + (w << 6);

    bf16x8 afrag[4][4];
#pragma unroll
    for (int r = 0; r < 4; ++r)
#pragma unroll
        for (int kk = 0; kk < 4; ++kk)
            afrag[r][kk] = *(const bf16x8*)(R + (size_t)(waveRow + r * 16 + lr) * D + kk * 32 + lk * 8);

    // staging: instruction j of wave w covers dest bytes (w*2+j)*1024 + lane*16
    int srcoff[2], dstoff[2];
#pragma unroll
    for (int j = 0; j < 2; ++j) {
        int o = (w * 2 + j) * 1024 + lane * 16;
        int row = o >> 8, c = o & 255;
        srcoff[j] = row * 256 + (c ^ ((row & 7) << 4)); // pre-swizzled global source
        dstoff[j] = (w * 2 + j) * 1024;                 // wave-uniform LDS base
    }

    const char* Rb = (const char*)R;

    // swizzled read-offset components: lds_off(ct,kk) = ct*4096 + lbase + (kk*64 ^ m64)
    int m64 = (lr & 4) << 4;
    int lbase = lr * 256 + ((lk * 16) ^ ((lr & 3) << 4));

    float acc[4][4] = {};
    f32x4 cv[2][4];                         // deferred MFMA results (static idx)

#define STAGE(buf, jj)                                                            \
    do {                                                                          \
        const char* tb_ = Rb + (size_t)(jj) * TILE_BYTES;                         \
        _Pragma("unroll")                                                         \
        for (int j = 0; j < 2; ++j)                                               \
            __builtin_amdgcn_global_load_lds(                                     \
                (const __attribute__((address_space(1))) unsigned*)(tb_ + srcoff[j]), \
                (__attribute__((address_space(3))) unsigned*)(&smem[buf][dstoff[j]]), \
                16, 0, 0);                                                        \
    } while (0)

    // fill cv from tile in smem[buf]: 8 ds_read_b128 then 32 MFMA
#define MFMA_BODY(buf)                                                            \
    do {                                                                          \
        const char* sb = &smem[buf][0] + lbase;                                   \
        bf16x8 bf[2][4];                                                          \
        _Pragma("unroll")                                                         \
        for (int ct = 0; ct < 2; ++ct)                                            \
            _Pragma("unroll")                                                     \
            for (int kk = 0; kk < 4; ++kk)                                        \
                bf[ct][kk] = *(const bf16x8*)(sb + ct * 4096 + ((kk * 64) ^ m64)); \
        _Pragma("unroll")                                                         \
        for (int ct = 0; ct < 2; ++ct) {                                          \
            _Pragma("unroll")                                                     \
            for (int r = 0; r < 4; ++r) {                                         \
                f32x4 c = {0.f, 0.f, 0.f, 0.f};                                   \
                c = __builtin_amdgcn_mfma_f32_16x16x32_bf16(afrag[r][0], bf[ct][0], c, 0, 0, 0); \
                c = __builtin_amdgcn_mfma_f32_16x16x32_bf16(afrag[r][1], bf[ct][1], c, 0, 0, 0); \
                c = __builtin_amdgcn_mfma_f32_16x16x32_bf16(afrag[r][2], bf[ct][2], c, 0, 0, 0); \
                c = __builtin_amdgcn_mfma_f32_16x16x32_bf16(afrag[r][3], bf[ct][3], c, 0, 0, 0); \
                cv[ct][r] = c;                                                    \
            }                                                                     \
        }                                                                         \
    } while (0)

    // consume cv (deferred tile): exp + acc + csum; PDG/pctd are the
    // deferred tile's diagonal parameters.
#define EXP_BODY(PDG)                                                             \
    do {                                                                          \
        _Pragma("unroll")                                                         \
        for (int ct = 0; ct < 2; ++ct) {                                          \
            _Pragma("unroll")                                                     \
            for (int r = 0; r < 4; ++r) {                                         \
                if (PDG && ct == r + pctd) {                                      \
                    _Pragma("unroll")                                             \
                    for (int q = 0; q < 4; ++q)                                   \
                        if (lk * 4 + q != lr) {                                   \
                            float e = fast_exp2(cv[ct][r][q]);                    \
                            acc[r][q] += e; csum[ct] += e;                        \
                        }                                                         \
                } else {                                                          \
                    _Pragma("unroll")                                             \
                    for (int q = 0; q < 4; ++q) {                                 \
                        float e = fast_exp2(cv[ct][r][q]);                        \
                        acc[r][q] += e; csum[ct] += e;                            \
                    }                                                             \
                }                                                                 \
            }                                                                     \
        }                                                                         \
    } while (0)

    // one rotating wave flushes colacc[par] for column-base pcb
#define FLUSH(pcb, par)                                                           \
    do {                                                                          \
        if ((pcb) >= rowBase + 256) {                                             \
            float v = 0.f;                                                        \
            _Pragma("unroll")                                                     \
            for (int u = 0; u < 16; ++u) v += colacc[par][u][lane & 15][lane >> 4]; \
            colpart[colpart_off(I) + (pcb) + lane - ((I + 1) << 8)] = v;          \
        }                                                                         \
    } while (0)

    if (nt > 0) {
        STAGE(0, jstart);
        __syncthreads();                     // drains vmcnt(0) before first reads
        int cur = 0;
        for (int t = 0; t < nt; ++t) {
            int jt = jstart + (t << 4);
            int colBase = jt << 5;
            // flush tile t-2's column partials (csum written at iter t-1,
            // barrier-separated; parity (t-2)&1 != (t-1)&1 -> no race)
            if (t > 1 && w == ((t + 3) & 3) && lane < 32)
                FLUSH(colBase - 1024, (t - 2) & 1);
            if (t + 1 < nt) STAGE(cur ^ 1, jt + 16);   // async prefetch
            const int pcolBase = colBase - 512;        // deferred tile t-1
            // issue tile t's ds_reads, then run tile t-1's epilogue under
            // their latency, then consume with MFMAs (cv rotates in place)
            {
                const char* sb = &smem[cur][0] + lbase;
                bf16x8 bf[2][4];
#pragma unroll
                for (int ct = 0; ct < 2; ++ct)
#pragma unroll
                    for (int kk = 0; kk < 4; ++kk)
                        bf[ct][kk] = *(const bf16x8*)(sb + ct * 4096 + ((kk * 64) ^ m64));
                if (t > 0) {                 // deferred epilogue of tile t-1
                    float csum[2] = {};
                    int pctd = (waveRow - pcolBase) >> 4;       // wave-uniform
                    bool pdg = (pctd == 0) || (pctd == -2);
                    if (pdg) { EXP_BODY(true); } else { EXP_BODY(false); }
                    if (pcolBase >= rowBase + 256) {            // offdiag
                        int par = (t - 1) & 1;
                        f32x2 cs = {csum[0], csum[1]};
                        *(f32x2*)&colacc[par][(w << 2) | lk][lr][0] = cs;
                    }
                }
#pragma unroll
                for (int ct = 0; ct < 2; ++ct) {
#pragma unroll
                    for (int r = 0; r < 4; ++r) {
                        f32x4 c = {0.f, 0.f, 0.f, 0.f};
                        c = __builtin_amdgcn_mfma_f32_16x16x32_bf16(afrag[r][0], bf[ct][0], c, 0, 0, 0);
                        c = __builtin_amdgcn_mfma_f32_16x16x32_bf16(afrag[r][1], bf[ct][1], c, 0, 0, 0);
                        c = __builtin_amdgcn_mfma_f32_16x16x32_bf16(afrag[r][2], bf[ct][2], c, 0, 0, 0);
                        c = __builtin_amdgcn_mfma_f32_16x16x32_bf16(afrag[r][3], bf[ct][3], c, 0, 0, 0);
                        cv[ct][r] = c;
                    }
                }
            }
            __syncthreads();                 // orders smem dbuf + colacc publish
            cur ^= 1;
        }
        // drain: epilogue of tile nt-1 (still in cv) + flush last two tiles
        {
            const int pcolBase = (jstart + ((nt - 1) << 4)) << 5;
            float csum[2] = {};
            int pctd = (waveRow - pcolBase) >> 4;
            bool pdg = (pctd == 0) || (pctd == -2);
            if (pdg) { EXP_BODY(true); } else { EXP_BODY(false); }
            if (pcolBase >= rowBase + 256) {
                int par = (nt - 1) & 1;
                f32x2 cs = {csum[0], csum[1]};
                *(f32x2*)&colacc[par][(w << 2) | lk][lr][0] = cs;
            }
        }
        __syncthreads();
        if (nt >= 2 && w == 0 && lane < 32)
            FLUSH((jstart + ((nt - 2) << 4)) << 5, (nt - 2) & 1);
        if (w == 1 && lane < 32)
            FLUSH((jstart + ((nt - 1) << 4)) << 5, (nt - 1) & 1);
    }
#undef STAGE
#undef MFMA_BODY
#undef EXP_BODY
#undef FLUSH

    // reduce the 16 col-lanes of each row group, write deterministic row partials
    // (empty lists still write zeros so k_negred can sum all 16 slabs)
#pragma unroll
    for (int r = 0; r < 4; ++r)
#pragma unroll
        for (int q = 0; q < 4; ++q) {
            float v = acc[r][q];
            v += __shfl_xor(v, 1);
            v += __shfl_xor(v, 2);
            v += __shfl_xor(v, 4);
            v += __shfl_xor(v, 8);
            if (lr == 0)
                rowpart[(size_t)s * NROWS + waveRow + r * 16 + lk * 4 + q] = v;
        }
}

// K2b: slice-parallel partial reduction of rowpart+colpart -> negp[8][N].
// 512 blocks; <=10 independent coalesced loads per thread.
__global__ __launch_bounds__(256) void k_negred(const float* __restrict__ rowpart,
                                                const float* __restrict__ colpart,
                                                float* __restrict__ negp) {
    int g = blockIdx.x >> 3;                // row group: rows [256g, 256g+256)
    int z = blockIdx.x & (NSLICE - 1);
    int i = g * 256 + threadIdx.x;
    float a = 0.f;
#pragma unroll
    for (int s = z; s < NSPLIT; s += NSLICE) // 2 iterations
        a += rowpart[(size_t)s * NROWS + i];
    for (int I = z; I < g; I += NSLICE)      // <=8 iterations, independent
        a += colpart[colpart_off(I) + i - ((I + 1) << 8)];
    negp[(size_t)z * NROWS + i] = a;
}

// K3a: per-row loss terms + block partial sums. 64 blocks x 256 threads.
__global__ __launch_bounds__(256) void k_loss1(const float* __restrict__ pos,
                                               const float* __restrict__ negp,
                                               float* __restrict__ bsum) {
    int i = blockIdx.x * 256 + threadIdx.x;
    float neg = 0.f;
#pragma unroll
    for (int z = 0; z < NSLICE; ++z) neg += negp[(size_t)z * NROWS + i];
    neg *= E_M2; // folded (sim - 2.0) shift
    float p = pos[i & (B_ROWS - 1)];
    float Ng = fmaxf((neg - 819.2f * p) * (1.0f / 0.9f), 8192.0f * E_M2);
    float l = fast_log2((p + Ng + 1e-8f) / p) * 0.69314718056f; // = -log(p/(p+Ng+eps))
#pragma unroll
    for (int m = 32; m; m >>= 1) l += __shfl_xor(l, m);
    __shared__ float s4[4];
    int wv = threadIdx.x >> 6;
    if ((threadIdx.x & 63) == 0) s4[wv] = l;
    __syncthreads();
    if (threadIdx.x == 0) bsum[blockIdx.x] = s4[0] + s4[1] + s4[2] + s4[3];
}

// K3b: final reduce of 64 block sums. 1 block, 1 wave (deterministic).
__global__ void k_loss2(const float* __restrict__ bsum, float* __restrict__ out) {
    float v = bsum[threadIdx.x];
#pragma unroll
    for (int m = 32; m; m >>= 1) v += __shfl_xor(v, m);
    if (threadIdx.x == 0) out[0] = v * (1.0f / (float)NROWS);
}

extern "C" void kernel_launch(void* const* d_in, const int* in_sizes, int n_in,
                              void* d_out, int out_size, void* d_ws, size_t ws_size,
                              hipStream_t stream) {
    const float* zi = (const float*)d_in[0];
    const float* zj = (const float*)d_in[1];
    char* ws = (char*)d_ws;
    unsigned short* reps = (unsigned short*)ws;            // 4 MB
    float* pos = (float*)(ws + 4194304);                   // 32 KB
    float* rowpart = pos + B_ROWS;                         // 16*16384*4 = 1 MB
    float* colpart = rowpart + (size_t)NSPLIT * NROWS;     // 516096*4 ~= 2 MB (triangular)
    float* negp = colpart + 516096;                        // 8*16384*4 = 512 KB
    float* bsum = negp + (size_t)NSLICE * NROWS;           // 256 B
    float* out = (float*)d_out;                            // total ~7.6 MB

    k_norm<<<B_ROWS / 4, 256, 0, stream>>>(zi, zj, (unsigned*)reps, pos);
    k_negsum<<<NBLK, 256, 0, stream>>>(reps, rowpart, colpart);
    k_negred<<<64 * NSLICE, 256, 0, stream>>>(rowpart, colpart, negp);
    k_loss1<<<NROWS / 256, 256, 0, stream>>>(pos, negp, bsum);
    k_loss2<<<1, 64, 0, stream>>>(bsum, out);
}

// Round 25
// 64.691 us; speedup vs baseline: 1.0505x; 1.0505x over previous
//
#include <hip/hip_runtime.h>
#include <hip/hip_bf16.h>

typedef __attribute__((ext_vector_type(8))) short bf16x8;
typedef __attribute__((ext_vector_type(4))) float f32x4;
typedef __attribute__((ext_vector_type(2))) float f32x2;

#define B_ROWS 8192
#define NROWS 16384             // 2B
#define D 128
#define C1 2.8853900817779268f  // 2*log2(e)  (sim = 2*cos; exp(x)=2^(x*log2e))
#define E_M2 0.13533528323661270f // exp(-2) == 2^(-C1): the folded row-max shift
#define RSCALE 1.6986436f       // sqrt(C1), folded into reps on both operands
#define TILE_COLS 32
#define TILE_BYTES (TILE_COLS * D * 2) // 8 KB per buffer
#define NSPLIT 16               // lists per row-chunk
#define NBLK (64 * NSPLIT)      // 1024
#define NSLICE 8

// Raw hardware exp2/log2: args are bounded, no range handling needed.
__device__ __forceinline__ float fast_exp2(float x) {
#if __has_builtin(__builtin_amdgcn_exp2f)
    return __builtin_amdgcn_exp2f(x);
#else
    float r; asm("v_exp_f32 %0, %1" : "=v"(r) : "v"(x)); return r;
#endif
}
__device__ __forceinline__ float fast_log2(float x) {
#if __has_builtin(__builtin_amdgcn_logf)
    return __builtin_amdgcn_logf(x);
#else
    float r; asm("v_log_f32 %0, %1" : "=v"(r) : "v"(x)); return r;
#endif
}

__device__ __forceinline__ unsigned short f2bf(float f) {
    union { float f; unsigned u; } v; v.f = f;
    unsigned r = v.u + 0x7FFFu + ((v.u >> 16) & 1u); // RNE
    return (unsigned short)(r >> 16);
}

// triangular colpart offset: slab I holds cols [256(I+1), NROWS)
__device__ __host__ __forceinline__ int colpart_off(int I) {
    return I * NROWS - 128 * I * (I + 1);
}

// K1: row norms + positive dots + bf16 reps (pre-scaled by sqrt(C1)).
__global__ __launch_bounds__(256) void k_norm(const float* __restrict__ zi,
                                              const float* __restrict__ zj,
                                              unsigned* __restrict__ repsU,
                                              float* __restrict__ pos) {
    int w = threadIdx.x >> 6, lane = threadIdx.x & 63;
    int row = blockIdx.x * 4 + w;
    const float2* a2 = (const float2*)(zi + (size_t)row * D);
    const float2* b2 = (const float2*)(zj + (size_t)row * D);
    float2 a = a2[lane], b = b2[lane];
    float si = a.x * a.x + a.y * a.y;
    float sj = b.x * b.x + b.y * b.y;
    float sd = a.x * b.x + a.y * b.y;
#pragma unroll
    for (int m = 32; m; m >>= 1) {
        si += __shfl_xor(si, m);
        sj += __shfl_xor(sj, m);
        sd += __shfl_xor(sd, m);
    }
    float inv_i = 1.0f / fmaxf(sqrtf(si), 1e-12f);
    float inv_j = 1.0f / fmaxf(sqrtf(sj), 1e-12f);
    float sa = inv_i * RSCALE, sb = inv_j * RSCALE;
    repsU[(size_t)row * 64 + lane] =
        (unsigned)f2bf(a.x * sa) | ((unsigned)f2bf(a.y * sa) << 16);
    repsU[(size_t)(row + B_ROWS) * 64 + lane] =
        (unsigned)f2bf(b.x * sb) | ((unsigned)f2bf(b.y * sb) << 16);
    if (lane == 0) pos[row] = fast_exp2(sd * inv_i * inv_j * C1); // exp(2*cos_ij)
}

// K2: symmetric-half fused sim-GEMM + exp + row/col sums (R18 plateau kernel,
// byte-identical; best measured config, reproduced at 54.1-54.8 us).
// 11 interventions falsified: barrier drain, counted-vmcnt, barrier-free
// ring, intra-block waves, cross-block TLP, tile x2, tile /2, 2-phase
// interleave, fence-fused tail, work rebalance, T15 epilogue deferral.
// The residual is the per-wave ds_read->MFMA->exp2 dep chain of this
// epilogue-heavy loop — beyond HIP source-level control.
// 20.5KB LDS, 32-col tiles, LDS dbuf + __syncthreads, pre-swizzled
// global_load_lds staging, I-major dispatch (L2 locality).
// C/D layout (m89-verified): row=(lane>>4)*4+q, col=lane&15.
__global__ __launch_bounds__(256, 2) void k_negsum(const unsigned short* __restrict__ R,
                                                   float* __restrict__ rowpart,
                                                   float* __restrict__ colpart) {
    __shared__ char smem[2][TILE_BYTES];    // 16 KB
    __shared__ float colacc[2][16][16][2];  // 4 KB [parity][w*4+lk][lr][ct]
    int I = blockIdx.x >> 4;
    int s = blockIdx.x & (NSPLIT - 1);
    int rowBase = I << 8;
    int j0 = I << 3;                        // first owned 32-col tile
    int dph = (s - (j0 & 15)) & 15;
    int jstart = j0 + dph;                  // first tile of this list
    int nt = (jstart < 512) ? (((511 - jstart) >> 4) + 1) : 0;

    int w = threadIdx.x >> 6;
    int lane = threadIdx.x & 63;
    int lr = lane & 15, lk = lane >> 4;
    int waveRow = rowBase + (w << 6);

    bf16x8 afrag[4][4];
#pragma unroll
    for (int r = 0; r < 4; ++r)
#pragma unroll
        for (int kk = 0; kk < 4; ++kk)
            afrag[r][kk] = *(const bf16x8*)(R + (size_t)(waveRow + r * 16 + lr) * D + kk * 32 + lk * 8);

    // staging: instruction j of wave w covers dest bytes (w*2+j)*1024 + lane*16
    int srcoff[2], dstoff[2];
#pragma unroll
    for (int j = 0; j < 2; ++j) {
        int o = (w * 2 + j) * 1024 + lane * 16;
        int row = o >> 8, c = o & 255;
        srcoff[j] = row * 256 + (c ^ ((row & 7) << 4)); // pre-swizzled global source
        dstoff[j] = (w * 2 + j) * 1024;                 // wave-uniform LDS base
    }

    const char* Rb = (const char*)R;

    // swizzled read-offset components: lds_off(ct,kk) = ct*4096 + lbase + (kk*64 ^ m64)
    int m64 = (lr & 4) << 4;
    int lbase = lr * 256 + ((lk * 16) ^ ((lr & 3) << 4));

    float acc[4][4] = {};

#define STAGE(buf, jj)                                                            \
    do {                                                                          \
        const char* tb_ = Rb + (size_t)(jj) * TILE_BYTES;                         \
        _Pragma("unroll")                                                         \
        for (int j = 0; j < 2; ++j)                                               \
            __builtin_amdgcn_global_load_lds(                                     \
                (const __attribute__((address_space(1))) unsigned*)(tb_ + srcoff[j]), \
                (__attribute__((address_space(3))) unsigned*)(&smem[buf][dstoff[j]]), \
                16, 0, 0);                                                        \
    } while (0)

    // ct in {0,1}; DIAG => mask subtile where ct == r + ctd (ctd in {0,-2})
#define BATCH_BODY(DIAG)                                                          \
    do {                                                                          \
        _Pragma("unroll")                                                         \
        for (int ct = 0; ct < 2; ++ct) {                                          \
            const char* cb_ = sb + ct * 4096;                                     \
            bf16x8 b0 = *(const bf16x8*)(cb_ + (0 ^ m64));                        \
            bf16x8 b1 = *(const bf16x8*)(cb_ + (64 ^ m64));                       \
            bf16x8 b2 = *(const bf16x8*)(cb_ + (128 ^ m64));                      \
            bf16x8 b3 = *(const bf16x8*)(cb_ + (192 ^ m64));                      \
            _Pragma("unroll")                                                     \
            for (int r = 0; r < 4; ++r) {                                         \
                f32x4 c = {0.f, 0.f, 0.f, 0.f};                                   \
                c = __builtin_amdgcn_mfma_f32_16x16x32_bf16(afrag[r][0], b0, c, 0, 0, 0); \
                c = __builtin_amdgcn_mfma_f32_16x16x32_bf16(afrag[r][1], b1, c, 0, 0, 0); \
                c = __builtin_amdgcn_mfma_f32_16x16x32_bf16(afrag[r][2], b2, c, 0, 0, 0); \
                c = __builtin_amdgcn_mfma_f32_16x16x32_bf16(afrag[r][3], b3, c, 0, 0, 0); \
                if (DIAG && ct == r + ctd) {                                      \
                    _Pragma("unroll")                                             \
                    for (int q = 0; q < 4; ++q)                                   \
                        if (lk * 4 + q != lr) {                                   \
                            float e = fast_exp2(c[q]);                            \
                            acc[r][q] += e; csum[ct] += e;                        \
                        }                                                         \
                } else {                                                          \
                    _Pragma("unroll")                                             \
                    for (int q = 0; q < 4; ++q) {                                 \
                        float e = fast_exp2(c[q]);                                \
                        acc[r][q] += e; csum[ct] += e;                            \
                    }                                                             \
                }                                                                 \
            }                                                                     \
        }                                                                         \
    } while (0)

    if (nt > 0) STAGE(0, jstart);
    __syncthreads();                         // drains vmcnt(0) before first reads
    int cur = 0;
    for (int t = 0; t < nt; ++t) {
        int jt = jstart + (t << 4);
        int colBase = jt << 5;
        // flush PREVIOUS tile's column partials (one rotating wave, lanes<32;
        // parity (t-1)&1 != t&1, so no race with this tile's colacc writes)
        if (t > 0 && w == ((t + 3) & 3) && lane < 32) {
            int pcb = colBase - 512;         // (jt-16)<<5
            if (pcb >= rowBase + 256) {
                int par = (t - 1) & 1;
                float v = 0.f;
#pragma unroll
                for (int u = 0; u < 16; ++u) v += colacc[par][u][lane & 15][lane >> 4];
                colpart[colpart_off(I) + pcb + lane - ((I + 1) << 8)] = v;
            }
        }
        if (t + 1 < nt) STAGE(cur ^ 1, jt + 16);   // async prefetch, zero VGPR cost
        const char* sb = &smem[cur][0] + lbase;
        float csum[2] = {};
        int ctd = (waveRow - colBase) >> 4;  // wave-uniform, multiple of 2
        bool dg = (ctd == 0) || (ctd == -2); // tile intersects wave's diagonal
        if (dg) {
            BATCH_BODY(true);
        } else {
            BATCH_BODY(false);
        }
        bool offdiag = (colBase >= rowBase + 256);
        if (offdiag) {                       // one b64 per lane, conflict-free
            int par = t & 1;
            f32x2 cs = {csum[0], csum[1]};
            *(f32x2*)&colacc[par][(w << 2) | lk][lr][0] = cs;
        }
        __syncthreads();                     // orders smem dbuf + colacc publish
        cur ^= 1;
    }
    if (nt > 0 && w == ((nt + 3) & 3) && lane < 32) { // flush last tile
        int pcb = (jstart + ((nt - 1) << 4)) << 5;
        if (pcb >= rowBase + 256) {
            int par = (nt - 1) & 1;
            float v = 0.f;
#pragma unroll
            for (int u = 0; u < 16; ++u) v += colacc[par][u][lane & 15][lane >> 4];
            colpart[colpart_off(I) + pcb + lane - ((I + 1) << 8)] = v;
        }
    }
#undef STAGE
#undef BATCH_BODY

    // reduce the 16 col-lanes of each row group, write deterministic row partials
    // (empty lists still write zeros so k_negred can sum all 16 slabs)
#pragma unroll
    for (int r = 0; r < 4; ++r)
#pragma unroll
        for (int q = 0; q < 4; ++q) {
            float v = acc[r][q];
            v += __shfl_xor(v, 1);
            v += __shfl_xor(v, 2);
            v += __shfl_xor(v, 4);
            v += __shfl_xor(v, 8);
            if (lr == 0)
                rowpart[(size_t)s * NROWS + waveRow + r * 16 + lk * 4 + q] = v;
        }
}

// K2b: slice-parallel partial reduction of rowpart+colpart -> negp[8][N].
// 512 blocks; <=10 independent coalesced loads per thread. (R19/R20 lessons:
// fusing this into fewer kernels loses — serial slab chain at 64 blocks, or
// device-fence storms with the last-block-done pattern. Stream-ordered
// launches are the cheapest ordering primitive on this chip.)
__global__ __launch_bounds__(256) void k_negred(const float* __restrict__ rowpart,
                                                const float* __restrict__ colpart,
                                                float* __restrict__ negp) {
    int g = blockIdx.x >> 3;                // row group: rows [256g, 256g+256)
    int z = blockIdx.x & (NSLICE - 1);
    int i = g * 256 + threadIdx.x;
    float a = 0.f;
#pragma unroll
    for (int s = z; s < NSPLIT; s += NSLICE) // 2 iterations
        a += rowpart[(size_t)s * NROWS + i];
    for (int I = z; I < g; I += NSLICE)      // <=8 iterations, independent
        a += colpart[colpart_off(I) + i - ((I + 1) << 8)];
    negp[(size_t)z * NROWS + i] = a;
}

// K3a: per-row loss terms + block partial sums. 64 blocks x 256 threads.
__global__ __launch_bounds__(256) void k_loss1(const float* __restrict__ pos,
                                               const float* __restrict__ negp,
                                               float* __restrict__ bsum) {
    int i = blockIdx.x * 256 + threadIdx.x;
    float neg = 0.f;
#pragma unroll
    for (int z = 0; z < NSLICE; ++z) neg += negp[(size_t)z * NROWS + i];
    neg *= E_M2; // folded (sim - 2.0) shift
    float p = pos[i & (B_ROWS - 1)];
    float Ng = fmaxf((neg - 819.2f * p) * (1.0f / 0.9f), 8192.0f * E_M2);
    float l = fast_log2((p + Ng + 1e-8f) / p) * 0.69314718056f; // = -log(p/(p+Ng+eps))
#pragma unroll
    for (int m = 32; m; m >>= 1) l += __shfl_xor(l, m);
    __shared__ float s4[4];
    int wv = threadIdx.x >> 6;
    if ((threadIdx.x & 63) == 0) s4[wv] = l;
    __syncthreads();
    if (threadIdx.x == 0) bsum[blockIdx.x] = s4[0] + s4[1] + s4[2] + s4[3];
}

// K3b: final reduce of 64 block sums. 1 block, 1 wave (deterministic).
__global__ void k_loss2(const float* __restrict__ bsum, float* __restrict__ out) {
    float v = bsum[threadIdx.x];
#pragma unroll
    for (int m = 32; m; m >>= 1) v += __shfl_xor(v, m);
    if (threadIdx.x == 0) out[0] = v * (1.0f / (float)NROWS);
}

extern "C" void kernel_launch(void* const* d_in, const int* in_sizes, int n_in,
                              void* d_out, int out_size, void* d_ws, size_t ws_size,
                              hipStream_t stream) {
    const float* zi = (const float*)d_in[0];
    const float* zj = (const float*)d_in[1];
    char* ws = (char*)d_ws;
    unsigned short* reps = (unsigned short*)ws;            // 4 MB
    float* pos = (float*)(ws + 4194304);                   // 32 KB
    float* rowpart = pos + B_ROWS;                         // 16*16384*4 = 1 MB
    float* colpart = rowpart + (size_t)NSPLIT * NROWS;     // 516096*4 ~= 2 MB (triangular)
    float* negp = colpart + 516096;                        // 8*16384*4 = 512 KB
    float* bsum = negp + (size_t)NSLICE * NROWS;           // 256 B
    float* out = (float*)d_out;                            // total ~7.6 MB

    k_norm<<<B_ROWS / 4, 256, 0, stream>>>(zi, zj, (unsigned*)reps, pos);
    k_negsum<<<NBLK, 256, 0, stream>>>(reps, rowpart, colpart);
    k_negred<<<64 * NSLICE, 256, 0, stream>>>(rowpart, colpart, negp);
    k_loss1<<<NROWS / 256, 256, 0, stream>>>(pos, negp, bsum);
    k_loss2<<<1, 64, 0, stream>>>(bsum, out);
}